// Round 7
// baseline (193.260 us; speedup 1.0000x reference)
//
#include <hip/hip_runtime.h>

// Problem constants (fixed by the reference)
constexpr int CH    = 384;    // channels
constexpr int NPIX  = 1024;   // H*W = 32*32
constexpr int NHEAD = 12;
constexpr int DH    = 32;     // head dim
constexpr int NB    = 16;     // batch
constexpr float SCALE = 0.17677669529663689f;  // 32^-0.5
constexpr float LOG2E = 1.4426950408889634f;

typedef __attribute__((ext_vector_type(8))) short bf16x8;  // 8 bf16 (4 VGPRs)
typedef __attribute__((ext_vector_type(4))) float f32x4;   // MFMA C/D frag

// pack two fp32 -> two bf16 (round-half-up), 3 VALU: 2 adds + v_perm_b32
__device__ __forceinline__ unsigned pk2(float a, float b) {
  return __builtin_amdgcn_perm(__float_as_uint(b) + 0x8000u,
                               __float_as_uint(a) + 0x8000u, 0x07060302u);
}
__device__ __forceinline__ unsigned short bf1(float a) {
  return (unsigned short)((__float_as_uint(a) + 0x8000u) >> 16);
}

// 2^x on the VALU (v_exp_f32 computes 2^x natively)
#if __has_builtin(__builtin_amdgcn_exp2f)
#define EXP2F(x) __builtin_amdgcn_exp2f(x)
#else
#define EXP2F(x) exp2f(x)
#endif

// async global->LDS, 16 B per lane; LDS dest = wave-uniform base + lane*16
#define GLOAD_LDS16(g, l)                                               \
  __builtin_amdgcn_global_load_lds(                                     \
      (const __attribute__((address_space(1))) unsigned int*)(g),       \
      (__attribute__((address_space(3))) unsigned int*)(l), 16, 0, 0)

// ---------------------------------------------------------------------------
// Prep: convert weights to bf16.  qkv_w rows o<384 (the Q block) pre-scaled
// by SCALE*log2(e): attention logits come out base-2 ready (softmax with
// 2^s == e^(s/log2e) -- identical distribution, saves a v_mul per exp).
// ---------------------------------------------------------------------------
__global__ __launch_bounds__(256) void prep_w(
    const float* __restrict__ qw, const float* __restrict__ pw,
    unsigned short* __restrict__ wq, unsigned short* __restrict__ pwq) {
  const int idx = blockIdx.x * 256 + threadIdx.x;
  if (idx < 110592) {
    float4 v = ((const float4*)qw)[idx];
    const int o = (idx * 4) / CH;  // 4 | 384: never crosses a row
    const float sc = (o < CH) ? SCALE * LOG2E : 1.0f;
    ((uint2*)wq)[idx] = (uint2){pk2(v.x * sc, v.y * sc), pk2(v.z * sc, v.w * sc)};
  } else {
    const int j = idx - 110592;
    float4 v = ((const float4*)pw)[j];
    ((uint2*)pwq)[j] = (uint2){pk2(v.x, v.y), pk2(v.z, v.w)};
  }
}

// ---------------------------------------------------------------------------
// Transpose x [b][c][n] fp32 -> xt [b][n][c] bf16 (K-major for MFMA B-operand)
// ---------------------------------------------------------------------------
__global__ __launch_bounds__(256) void transpose_x(
    const float* __restrict__ x, unsigned short* __restrict__ xt) {
  __shared__ float T[64][65];
  const int b = blockIdx.z, c0 = blockIdx.y * 64, n0 = blockIdx.x * 64;
  const int tid = threadIdx.x;
  const float* xb = x + ((size_t)b * CH + c0) * NPIX + n0;
  const int rn = (tid & 15) * 4, rc = tid >> 4;
#pragma unroll
  for (int i = 0; i < 4; i++) {
    float4 v = *(const float4*)(xb + (size_t)(rc + i * 16) * NPIX + rn);
    T[rc + i * 16][rn + 0] = v.x;
    T[rc + i * 16][rn + 1] = v.y;
    T[rc + i * 16][rn + 2] = v.z;
    T[rc + i * 16][rn + 3] = v.w;
  }
  __syncthreads();
  unsigned short* xo = xt + ((size_t)b * NPIX + n0) * CH + c0;
  const int wc = (tid & 15) * 4, wn = tid >> 4;
#pragma unroll
  for (int i = 0; i < 4; i++) {
    const int n = wn + i * 16;
    uint2 p = {pk2(T[wc][n], T[wc + 1][n]), pk2(T[wc + 2][n], T[wc + 3][n])};
    *(uint2*)(xo + (size_t)n * CH + wc) = p;
  }
}

// ---------------------------------------------------------------------------
// QKV GEMM, bf16 MFMA.  Per batch b:
//   Y[o,n] = sum_c Wq[o,c] * XT[n,c],  M=1152, N=1024, K=384
// For V-blocks (blockIdx.y/3 == 2) the MFMA operands are SWAPPED (A=pixels,
// B=weights) so the C-frag's 4-consecutive-rows-per-reg become consecutive
// PIXELS: the d-major vtb[d][n] store is then 16 uint2 per lane instead of
// 64 scalar shorts.
// ---------------------------------------------------------------------------
__global__ __launch_bounds__(256) void qkv_mfma(
    const unsigned short* __restrict__ xt, const unsigned short* __restrict__ wq,
    unsigned short* __restrict__ qb, unsigned short* __restrict__ kb,
    unsigned short* __restrict__ vtb) {
  __shared__ unsigned short As[128 * 32];  // [m(o)][k] rows of 64 B
  __shared__ unsigned short Bs[128 * 32];  // [n(pix)][k]
  const int b = blockIdx.z;
  const int m0 = blockIdx.y * 128;
  const int n0 = blockIdx.x * 128;
  const int tid = threadIdx.x, wave = tid >> 6, lane = tid & 63;
  const int wm = (wave >> 1) * 64, wn = (wave & 1) * 64;
  const int cc = lane & 15, quad = lane >> 4;
  const int qkv_t = blockIdx.y / 3;  // 0=Q, 1=K, 2=V

  const unsigned short* agp =
      wq + (size_t)(m0 + wave * 16 + (lane >> 2)) * CH + (lane & 3) * 8;
  const unsigned short* bgp =
      xt + ((size_t)b * NPIX + n0 + wave * 16 + (lane >> 2)) * CH + (lane & 3) * 8;
  unsigned short* al = As + wave * 16 * 32;
  unsigned short* bl = Bs + wave * 16 * 32;

  f32x4 acc[4][4];
#pragma unroll
  for (int i = 0; i < 4; i++)
#pragma unroll
    for (int j = 0; j < 4; j++) acc[i][j] = (f32x4){0.f, 0.f, 0.f, 0.f};

  for (int k0 = 0; k0 < CH; k0 += 32) {
    GLOAD_LDS16(agp + k0, al);
    GLOAD_LDS16(agp + k0 + (size_t)64 * CH, al + 64 * 32);
    GLOAD_LDS16(bgp + k0, bl);
    GLOAD_LDS16(bgp + k0 + (size_t)64 * CH, bl + 64 * 32);
    __syncthreads();
    bf16x8 af[4], bfr[4];
    if (qkv_t < 2) {
#pragma unroll
      for (int t = 0; t < 4; t++)
        af[t] = *(const bf16x8*)(As + (wm + t * 16 + cc) * 32 + quad * 8);
#pragma unroll
      for (int t = 0; t < 4; t++)
        bfr[t] = *(const bf16x8*)(Bs + (wn + t * 16 + cc) * 32 + quad * 8);
    } else {  // V: swap roles -> C rows = pixels
#pragma unroll
      for (int t = 0; t < 4; t++)
        af[t] = *(const bf16x8*)(Bs + (wn + t * 16 + cc) * 32 + quad * 8);
#pragma unroll
      for (int t = 0; t < 4; t++)
        bfr[t] = *(const bf16x8*)(As + (wm + t * 16 + cc) * 32 + quad * 8);
    }
#pragma unroll
    for (int i = 0; i < 4; i++)
#pragma unroll
      for (int j = 0; j < 4; j++)
        acc[i][j] = __builtin_amdgcn_mfma_f32_16x16x32_bf16(af[i], bfr[j], acc[i][j], 0, 0, 0);
    __syncthreads();
  }

  const int obase = m0 - qkv_t * CH;  // 0/128/256 within the Q/K/V segment
  if (qkv_t < 2) {
    unsigned short* dst0 = (qkv_t == 0) ? qb : kb;
#pragma unroll
    for (int mt = 0; mt < 4; mt++) {
      const int o = obase + wm + mt * 16 + quad * 4;  // [0,384)
      const int h = o >> 5, d0 = o & 31;
      unsigned short* drow = dst0 + ((size_t)(b * NHEAD + h) * NPIX) * DH + d0;
#pragma unroll
      for (int nt = 0; nt < 4; nt++) {
        const int n = n0 + wn + nt * 16 + cc;
        uint2 p = {pk2(acc[mt][nt][0], acc[mt][nt][1]),
                   pk2(acc[mt][nt][2], acc[mt][nt][3])};
        *(uint2*)(drow + (size_t)n * DH) = p;
      }
    }
  } else {
    // acc[i][j] reg r: pixel n = n0 + wn + i*16 + quad*4 + r,
    //                  output o = obase + wm + j*16 + cc
#pragma unroll
    for (int i = 0; i < 4; i++) {
      const int nbase = n0 + wn + i * 16 + quad * 4;
#pragma unroll
      for (int j = 0; j < 4; j++) {
        const int od = obase + wm + j * 16 + cc;
        const int h = od >> 5, dd = od & 31;
        unsigned short* vrow = vtb + ((size_t)(b * NHEAD + h) * DH + dd) * NPIX;
        *(uint2*)(vrow + nbase) = (uint2){pk2(acc[i][j][0], acc[i][j][1]),
                                          pk2(acc[i][j][2], acc[i][j][3])};
      }
    }
  }
}

// ---------------------------------------------------------------------------
// MFMA attention v6.  One wave = 32 query rows (2 q-groups); grid (bh, 8)
// gives 1536 blocks = 6 blocks/CU = 6 waves/SIMD (2x R6's residency).
// Skewed software pipeline (PV consumes the previous iteration's P/V regs;
// ds_read latency is off the critical path).  Softmax in base 2: Q was
// pre-scaled by SCALE*log2e, so p = v_exp_f32(s) directly.
// Grid x-major keeps all blocks of one (b,h) on one XCD (192%8==0).
// ---------------------------------------------------------------------------
__global__ __launch_bounds__(256, 6) void attn_mfma(
    const unsigned short* __restrict__ qb, const unsigned short* __restrict__ kb,
    const unsigned short* __restrict__ vtb, unsigned short* __restrict__ ao) {
  constexpr int PSTR = 36;  // 72 B rows: 18c mod 32 hits all 16 even residues
  __shared__ unsigned short Pbuf[4][2][16][PSTR];  // [wave][qgroup][row][keys]

  const int bh   = blockIdx.x;  // 0..191  (x-major -> XCD = bh % 8)
  const int b    = bh / NHEAD;
  const int h    = bh - b * NHEAD;
  const int tid  = threadIdx.x;
  const int wave = tid >> 6;
  const int lane = tid & 63;
  const int c    = lane & 15;
  const int Q0   = lane >> 4;
  const int q0   = blockIdx.y * 128 + wave * 32;

  bf16x8 Bq[2];
#pragma unroll
  for (int g = 0; g < 2; g++)
    Bq[g] = *(const bf16x8*)(qb + ((size_t)bh * NPIX + q0 + 16 * g + c) * DH + Q0 * 8);

  const unsigned short* kbase = kb + (size_t)bh * NPIX * DH;
  const unsigned short* vrow0 = vtb + ((size_t)bh * DH + c) * NPIX;
  const unsigned short* vrow1 = vtb + ((size_t)bh * DH + c + 16) * NPIX;

  const f32x4 zero = {0.f, 0.f, 0.f, 0.f};
  const bf16x8 zero8 = {0, 0, 0, 0, 0, 0, 0, 0};
  f32x4 o0[2] = {zero, zero}, o1[2] = {zero, zero};
  float lsum[2] = {0.f, 0.f};

  unsigned short* prow[2];
#pragma unroll
  for (int g = 0; g < 2; g++) prow[g] = &Pbuf[wave][g][c][0];

  // pipeline registers
  bf16x8 Ka0 = *(const bf16x8*)(kbase + (size_t)c * DH + Q0 * 8);  // K(0)
  bf16x8 Ka1 = *(const bf16x8*)(kbase + (size_t)(16 + c) * DH + Q0 * 8);
  bf16x8 Vr0 = zero8, Vr1 = zero8;       // V(t-1); zero so PV(-1) adds 0
  bf16x8 Bp[2] = {zero8, zero8};         // P(t-1)

#pragma unroll 2
  for (int kt = 0; kt < NPIX; kt += 32) {
    // prefetch K(t+1) (wraps harmlessly) and V(t)
    const int kt2 = (kt + 32) & (NPIX - 1);
    bf16x8 nKa0 = *(const bf16x8*)(kbase + (size_t)(kt2 + c) * DH + Q0 * 8);
    bf16x8 nKa1 = *(const bf16x8*)(kbase + (size_t)(kt2 + 16 + c) * DH + Q0 * 8);
    bf16x8 nVa0 = *(const bf16x8*)(vrow0 + kt + Q0 * 8);
    bf16x8 nVa1 = *(const bf16x8*)(vrow1 + kt + Q0 * 8);

    // S(t) = K(t) . Q^T
    f32x4 s0[2], s1[2];
#pragma unroll
    for (int g = 0; g < 2; g++) {
      s0[g] = __builtin_amdgcn_mfma_f32_16x16x32_bf16(Ka0, Bq[g], zero, 0, 0, 0);
      s1[g] = __builtin_amdgcn_mfma_f32_16x16x32_bf16(Ka1, Bq[g], zero, 0, 0, 0);
    }

    // PV(t-1): operands already in registers
#pragma unroll
    for (int g = 0; g < 2; g++) {
      o0[g] = __builtin_amdgcn_mfma_f32_16x16x32_bf16(Vr0, Bp[g], o0[g], 0, 0, 0);
      o1[g] = __builtin_amdgcn_mfma_f32_16x16x32_bf16(Vr1, Bp[g], o1[g], 0, 0, 0);
    }

    // p = 2^s (Q pre-scaled by log2e), lsum, pack, LDS round-trip
#pragma unroll
    for (int g = 0; g < 2; g++) {
      float p0[4], p1[4];
#pragma unroll
      for (int r = 0; r < 4; r++) { p0[r] = EXP2F(s0[g][r]); lsum[g] += p0[r]; }
#pragma unroll
      for (int r = 0; r < 4; r++) { p1[r] = EXP2F(s1[g][r]); lsum[g] += p1[r]; }
      *(uint2*)(prow[g] + 4 * Q0)      = (uint2){pk2(p0[0], p0[1]), pk2(p0[2], p0[3])};
      *(uint2*)(prow[g] + 16 + 4 * Q0) = (uint2){pk2(p1[0], p1[1]), pk2(p1[2], p1[3])};
    }
#pragma unroll
    for (int g = 0; g < 2; g++) Bp[g] = *(const bf16x8*)(prow[g] + 8 * Q0);

    Ka0 = nKa0; Ka1 = nKa1; Vr0 = nVa0; Vr1 = nVa1;
  }

  // drain: PV(last)
#pragma unroll
  for (int g = 0; g < 2; g++) {
    o0[g] = __builtin_amdgcn_mfma_f32_16x16x32_bf16(Vr0, Bp[g], o0[g], 0, 0, 0);
    o1[g] = __builtin_amdgcn_mfma_f32_16x16x32_bf16(Vr1, Bp[g], o1[g], 0, 0, 0);
  }

#pragma unroll
  for (int g = 0; g < 2; g++) {
    float l = lsum[g];
    l += __shfl_xor(l, 16);
    l += __shfl_xor(l, 32);
    const float inv = 1.0f / l;
    unsigned short* op =
        ao + ((size_t)(b * NPIX + q0 + 16 * g + c)) * CH + h * DH + 4 * Q0;
    *(uint2*)op = (uint2){pk2(o0[g][0] * inv, o0[g][1] * inv),
                          pk2(o0[g][2] * inv, o0[g][3] * inv)};
    *(uint2*)(op + 16) = (uint2){pk2(o1[g][0] * inv, o1[g][1] * inv),
                                 pk2(o1[g][2] * inv, o1[g][3] * inv)};
  }
}

// ---------------------------------------------------------------------------
// Output projection, bf16 MFMA.  Per batch b:
//   out[c][n] = sum_{c'} Pw[c,c'] * AO[n,c'] + bias[c],  M=384,N=1024,K=384
// ---------------------------------------------------------------------------
__global__ __launch_bounds__(256) void proj_mfma(
    const unsigned short* __restrict__ ao, const unsigned short* __restrict__ pwq,
    const float* __restrict__ bias, float* __restrict__ out) {
  __shared__ unsigned short As[128 * 32];
  __shared__ unsigned short Bs[128 * 32];
  const int b = blockIdx.z;
  const int m0 = blockIdx.y * 128;
  const int n0 = blockIdx.x * 128;
  const int tid = threadIdx.x, wave = tid >> 6, lane = tid & 63;
  const int wm = (wave >> 1) * 64, wn = (wave & 1) * 64;
  const int cc = lane & 15, quad = lane >> 4;

  const unsigned short* agp =
      pwq + (size_t)(m0 + wave * 16 + (lane >> 2)) * CH + (lane & 3) * 8;
  const unsigned short* bgp =
      ao + ((size_t)b * NPIX + n0 + wave * 16 + (lane >> 2)) * CH + (lane & 3) * 8;
  unsigned short* al = As + wave * 16 * 32;
  unsigned short* bl = Bs + wave * 16 * 32;

  f32x4 acc[4][4];
#pragma unroll
  for (int i = 0; i < 4; i++)
#pragma unroll
    for (int j = 0; j < 4; j++) acc[i][j] = (f32x4){0.f, 0.f, 0.f, 0.f};

  for (int k0 = 0; k0 < CH; k0 += 32) {
    GLOAD_LDS16(agp + k0, al);
    GLOAD_LDS16(agp + k0 + (size_t)64 * CH, al + 64 * 32);
    GLOAD_LDS16(bgp + k0, bl);
    GLOAD_LDS16(bgp + k0 + (size_t)64 * CH, bl + 64 * 32);
    __syncthreads();
    bf16x8 af[4], bfr[4];
#pragma unroll
    for (int t = 0; t < 4; t++)
      af[t] = *(const bf16x8*)(As + (wm + t * 16 + cc) * 32 + quad * 8);
#pragma unroll
    for (int t = 0; t < 4; t++)
      bfr[t] = *(const bf16x8*)(Bs + (wn + t * 16 + cc) * 32 + quad * 8);
#pragma unroll
    for (int i = 0; i < 4; i++)
#pragma unroll
      for (int j = 0; j < 4; j++)
        acc[i][j] = __builtin_amdgcn_mfma_f32_16x16x32_bf16(af[i], bfr[j], acc[i][j], 0, 0, 0);
    __syncthreads();
  }

#pragma unroll
  for (int mt = 0; mt < 4; mt++) {
    const int cbase = m0 + wm + mt * 16 + quad * 4;
    const float4 bi4 = *(const float4*)(bias + cbase);
#pragma unroll
    for (int nt = 0; nt < 4; nt++) {
      const int n = n0 + wn + nt * 16 + cc;
      float* op = out + ((size_t)b * CH + cbase) * NPIX + n;
      op[0 * NPIX] = acc[mt][nt][0] + bi4.x;
      op[1 * NPIX] = acc[mt][nt][1] + bi4.y;
      op[2 * NPIX] = acc[mt][nt][2] + bi4.z;
      op[3 * NPIX] = acc[mt][nt][3] + bi4.w;
    }
  }
}

extern "C" void kernel_launch(void* const* d_in, const int* in_sizes, int n_in,
                              void* d_out, int out_size, void* d_ws, size_t ws_size,
                              hipStream_t stream) {
  const float* x      = (const float*)d_in[0];  // [16,384,32,32]
  const float* qkv_w  = (const float*)d_in[1];  // [1152,384]
  const float* proj_w = (const float*)d_in[2];  // [384,384]
  const float* proj_b = (const float*)d_in[3];  // [384]

  constexpr size_t SEG = (size_t)NB * NPIX * CH;  // 6291456
  unsigned short* ws  = (unsigned short*)d_ws;
  unsigned short* xtw = ws;
  unsigned short* qbw = ws + SEG;
  unsigned short* kbw = ws + 2 * SEG;
  unsigned short* vtw = ws + 3 * SEG;
  unsigned short* aow = ws + 4 * SEG;
  unsigned short* wqw = ws + 5 * SEG;               // 442368
  unsigned short* pww = wqw + (size_t)3 * CH * CH;  // 147456

  prep_w<<<576, 256, 0, stream>>>(qkv_w, proj_w, wqw, pww);
  transpose_x<<<dim3(NPIX / 64, CH / 64, NB), 256, 0, stream>>>(x, xtw);
  qkv_mfma<<<dim3(NPIX / 128, (3 * CH) / 128, NB), 256, 0, stream>>>(xtw, wqw, qbw, kbw, vtw);
  // grid (bh, qtile): same-bh blocks share an XCD -> K/V L2-resident
  attn_mfma<<<dim3(NB * NHEAD, NPIX / 128), 256, 0, stream>>>(qbw, kbw, vtw, aow);
  proj_mfma<<<dim3(NPIX / 128, CH / 128, NB), 256, 0, stream>>>(aow, pww, proj_b, (float*)d_out);
}

// Round 8
// 180.454 us; speedup vs baseline: 1.0710x; 1.0710x over previous
//
#include <hip/hip_runtime.h>

// Problem constants (fixed by the reference)
constexpr int CH    = 384;    // channels
constexpr int NPIX  = 1024;   // H*W = 32*32
constexpr int NHEAD = 12;
constexpr int DH    = 32;     // head dim
constexpr int NB    = 16;     // batch
constexpr float SCALE = 0.17677669529663689f;  // 32^-0.5
constexpr float LOG2E = 1.4426950408889634f;

typedef __attribute__((ext_vector_type(8))) short bf16x8;  // 8 bf16 (4 VGPRs)
typedef __attribute__((ext_vector_type(4))) float f32x4;   // MFMA C/D frag

// pack two fp32 -> two bf16 (round-half-up), 3 VALU: 2 adds + v_perm_b32
__device__ __forceinline__ unsigned pk2(float a, float b) {
  return __builtin_amdgcn_perm(__float_as_uint(b) + 0x8000u,
                               __float_as_uint(a) + 0x8000u, 0x07060302u);
}
__device__ __forceinline__ unsigned short bf1(float a) {
  return (unsigned short)((__float_as_uint(a) + 0x8000u) >> 16);
}

// 2^x on the VALU (v_exp_f32 computes 2^x natively)
#if __has_builtin(__builtin_amdgcn_exp2f)
#define EXP2F(x) __builtin_amdgcn_exp2f(x)
#else
#define EXP2F(x) exp2f(x)
#endif

// async global->LDS, 16 B per lane; LDS dest = wave-uniform base + lane*16
#define GLOAD_LDS16(g, l)                                               \
  __builtin_amdgcn_global_load_lds(                                     \
      (const __attribute__((address_space(1))) unsigned int*)(g),       \
      (__attribute__((address_space(3))) unsigned int*)(l), 16, 0, 0)

// ---------------------------------------------------------------------------
// Prep: convert weights to bf16.  qkv_w rows o<384 (the Q block) pre-scaled
// by SCALE*log2(e): logits come out base-2 ready (2^s softmax == e^s softmax).
// ---------------------------------------------------------------------------
__global__ __launch_bounds__(256) void prep_w(
    const float* __restrict__ qw, const float* __restrict__ pw,
    unsigned short* __restrict__ wq, unsigned short* __restrict__ pwq) {
  const int idx = blockIdx.x * 256 + threadIdx.x;
  if (idx < 110592) {
    float4 v = ((const float4*)qw)[idx];
    const int o = (idx * 4) / CH;  // 4 | 384: never crosses a row
    const float sc = (o < CH) ? SCALE * LOG2E : 1.0f;
    ((uint2*)wq)[idx] = (uint2){pk2(v.x * sc, v.y * sc), pk2(v.z * sc, v.w * sc)};
  } else {
    const int j = idx - 110592;
    float4 v = ((const float4*)pw)[j];
    ((uint2*)pwq)[j] = (uint2){pk2(v.x, v.y), pk2(v.z, v.w)};
  }
}

// ---------------------------------------------------------------------------
// Transpose x [b][c][n] fp32 -> xt [b][n][c] bf16 (K-major for MFMA B-operand)
// ---------------------------------------------------------------------------
__global__ __launch_bounds__(256) void transpose_x(
    const float* __restrict__ x, unsigned short* __restrict__ xt) {
  __shared__ float T[64][65];
  const int b = blockIdx.z, c0 = blockIdx.y * 64, n0 = blockIdx.x * 64;
  const int tid = threadIdx.x;
  const float* xb = x + ((size_t)b * CH + c0) * NPIX + n0;
  const int rn = (tid & 15) * 4, rc = tid >> 4;
#pragma unroll
  for (int i = 0; i < 4; i++) {
    float4 v = *(const float4*)(xb + (size_t)(rc + i * 16) * NPIX + rn);
    T[rc + i * 16][rn + 0] = v.x;
    T[rc + i * 16][rn + 1] = v.y;
    T[rc + i * 16][rn + 2] = v.z;
    T[rc + i * 16][rn + 3] = v.w;
  }
  __syncthreads();
  unsigned short* xo = xt + ((size_t)b * NPIX + n0) * CH + c0;
  const int wc = (tid & 15) * 4, wn = tid >> 4;
#pragma unroll
  for (int i = 0; i < 4; i++) {
    const int n = wn + i * 16;
    uint2 p = {pk2(T[wc][n], T[wc + 1][n]), pk2(T[wc + 2][n], T[wc + 3][n])};
    *(uint2*)(xo + (size_t)n * CH + wc) = p;
  }
}

// ---------------------------------------------------------------------------
// QKV GEMM, bf16 MFMA.  Per batch b:
//   Y[o,n] = sum_c Wq[o,c] * XT[n,c],  M=1152, N=1024, K=384
// V-blocks swap MFMA operands so C-frag rows = consecutive pixels ->
// vectorized d-major stores.
// ---------------------------------------------------------------------------
__global__ __launch_bounds__(256) void qkv_mfma(
    const unsigned short* __restrict__ xt, const unsigned short* __restrict__ wq,
    unsigned short* __restrict__ qb, unsigned short* __restrict__ kb,
    unsigned short* __restrict__ vtb) {
  __shared__ unsigned short As[128 * 32];  // [m(o)][k] rows of 64 B
  __shared__ unsigned short Bs[128 * 32];  // [n(pix)][k]
  const int b = blockIdx.z;
  const int m0 = blockIdx.y * 128;
  const int n0 = blockIdx.x * 128;
  const int tid = threadIdx.x, wave = tid >> 6, lane = tid & 63;
  const int wm = (wave >> 1) * 64, wn = (wave & 1) * 64;
  const int cc = lane & 15, quad = lane >> 4;
  const int qkv_t = blockIdx.y / 3;  // 0=Q, 1=K, 2=V

  const unsigned short* agp =
      wq + (size_t)(m0 + wave * 16 + (lane >> 2)) * CH + (lane & 3) * 8;
  const unsigned short* bgp =
      xt + ((size_t)b * NPIX + n0 + wave * 16 + (lane >> 2)) * CH + (lane & 3) * 8;
  unsigned short* al = As + wave * 16 * 32;
  unsigned short* bl = Bs + wave * 16 * 32;

  f32x4 acc[4][4];
#pragma unroll
  for (int i = 0; i < 4; i++)
#pragma unroll
    for (int j = 0; j < 4; j++) acc[i][j] = (f32x4){0.f, 0.f, 0.f, 0.f};

  for (int k0 = 0; k0 < CH; k0 += 32) {
    GLOAD_LDS16(agp + k0, al);
    GLOAD_LDS16(agp + k0 + (size_t)64 * CH, al + 64 * 32);
    GLOAD_LDS16(bgp + k0, bl);
    GLOAD_LDS16(bgp + k0 + (size_t)64 * CH, bl + 64 * 32);
    __syncthreads();
    bf16x8 af[4], bfr[4];
    if (qkv_t < 2) {
#pragma unroll
      for (int t = 0; t < 4; t++)
        af[t] = *(const bf16x8*)(As + (wm + t * 16 + cc) * 32 + quad * 8);
#pragma unroll
      for (int t = 0; t < 4; t++)
        bfr[t] = *(const bf16x8*)(Bs + (wn + t * 16 + cc) * 32 + quad * 8);
    } else {  // V: swap roles -> C rows = pixels
#pragma unroll
      for (int t = 0; t < 4; t++)
        af[t] = *(const bf16x8*)(Bs + (wn + t * 16 + cc) * 32 + quad * 8);
#pragma unroll
      for (int t = 0; t < 4; t++)
        bfr[t] = *(const bf16x8*)(As + (wm + t * 16 + cc) * 32 + quad * 8);
    }
#pragma unroll
    for (int i = 0; i < 4; i++)
#pragma unroll
      for (int j = 0; j < 4; j++)
        acc[i][j] = __builtin_amdgcn_mfma_f32_16x16x32_bf16(af[i], bfr[j], acc[i][j], 0, 0, 0);
    __syncthreads();
  }

  const int obase = m0 - qkv_t * CH;  // 0/128/256 within the Q/K/V segment
  if (qkv_t < 2) {
    unsigned short* dst0 = (qkv_t == 0) ? qb : kb;
#pragma unroll
    for (int mt = 0; mt < 4; mt++) {
      const int o = obase + wm + mt * 16 + quad * 4;  // [0,384)
      const int h = o >> 5, d0 = o & 31;
      unsigned short* drow = dst0 + ((size_t)(b * NHEAD + h) * NPIX) * DH + d0;
#pragma unroll
      for (int nt = 0; nt < 4; nt++) {
        const int n = n0 + wn + nt * 16 + cc;
        uint2 p = {pk2(acc[mt][nt][0], acc[mt][nt][1]),
                   pk2(acc[mt][nt][2], acc[mt][nt][3])};
        *(uint2*)(drow + (size_t)n * DH) = p;
      }
    }
  } else {
#pragma unroll
    for (int i = 0; i < 4; i++) {
      const int nbase = n0 + wn + i * 16 + quad * 4;
#pragma unroll
      for (int j = 0; j < 4; j++) {
        const int od = obase + wm + j * 16 + cc;
        const int h = od >> 5, dd = od & 31;
        unsigned short* vrow = vtb + ((size_t)(b * NHEAD + h) * DH + dd) * NPIX;
        *(uint2*)(vrow + nbase) = (uint2){pk2(acc[i][j][0], acc[i][j][1]),
                                          pk2(acc[i][j][2], acc[i][j][3])};
      }
    }
  }
}

// ---------------------------------------------------------------------------
// MFMA attention v7: split-K wave pairs.
// Block = 4 waves = 2 q-subtiles x 2 key-halves.  Each wave: 64 queries
// (4 q-groups, R6's best amortization: 16 MFMA per 4 K/V loads) over 512
// keys (16 iterations).  Wave pair (2p, 2p+1) covers key halves [0,512) /
// [512,1024) of the same queries; unnormalized partials (O, l) add exactly,
// combined through LDS (reuses Pbuf after a barrier).
// Grid (192, 8) = 1536 blocks = 6 blocks/CU (2x R6's residency), x-major
// keeps all blocks of one (b,h) on one XCD (192%8==0) -> K/V L2-resident.
// Skewed pipeline: PV(t-1) consumes registers; ds_read off critical path.
// Base-2 softmax (Q pre-scaled by SCALE*log2e).
// ---------------------------------------------------------------------------
__global__ __launch_bounds__(256, 4) void attn_mfma(
    const unsigned short* __restrict__ qb, const unsigned short* __restrict__ kb,
    const unsigned short* __restrict__ vtb, unsigned short* __restrict__ ao) {
  constexpr int PSTR = 36;  // 72 B rows: 18c mod 32 hits all 16 even residues
  // 18432 B; doubles as the combine buffer (1152 float4) after the barrier
  __shared__ __align__(16) unsigned short Pbuf[4][4][16][PSTR];

  const int bh   = blockIdx.x;  // 0..191  (x-major -> XCD = bh % 8)
  const int b    = bh / NHEAD;
  const int h    = bh - b * NHEAD;
  const int tid  = threadIdx.x;
  const int wave = tid >> 6;
  const int half = wave & 1;          // key half
  const int pairq = wave >> 1;        // q-subtile within block
  const int lane = tid & 63;
  const int c    = lane & 15;
  const int Q0   = lane >> 4;
  const int q0   = blockIdx.y * 128 + pairq * 64;

  bf16x8 Bq[4];
#pragma unroll
  for (int g = 0; g < 4; g++)
    Bq[g] = *(const bf16x8*)(qb + ((size_t)bh * NPIX + q0 + 16 * g + c) * DH + Q0 * 8);

  const unsigned short* kh  = kb + ((size_t)bh * NPIX + half * 512) * DH;
  const unsigned short* v0h = vtb + ((size_t)bh * DH + c) * NPIX + half * 512;
  const unsigned short* v1h = vtb + ((size_t)bh * DH + c + 16) * NPIX + half * 512;

  const f32x4 zero = {0.f, 0.f, 0.f, 0.f};
  const bf16x8 zero8 = {0, 0, 0, 0, 0, 0, 0, 0};
  f32x4 o0[4], o1[4];
  float lsum[4];
#pragma unroll
  for (int g = 0; g < 4; g++) { o0[g] = zero; o1[g] = zero; lsum[g] = 0.f; }

  unsigned short* prow[4];
#pragma unroll
  for (int g = 0; g < 4; g++) prow[g] = &Pbuf[wave][g][c][0];

  // pipeline registers
  bf16x8 Ka0 = *(const bf16x8*)(kh + (size_t)c * DH + Q0 * 8);  // K(0)
  bf16x8 Ka1 = *(const bf16x8*)(kh + (size_t)(16 + c) * DH + Q0 * 8);
  bf16x8 Vr0 = zero8, Vr1 = zero8;              // V(t-1); PV(-1) adds 0
  bf16x8 Bp[4] = {zero8, zero8, zero8, zero8};  // P(t-1)

#pragma unroll 2
  for (int kt = 0; kt < 512; kt += 32) {
    const int kt2 = (kt + 32) & 511;  // wrap on last iter (redundant, in-bounds)
    bf16x8 nKa0 = *(const bf16x8*)(kh + (size_t)(kt2 + c) * DH + Q0 * 8);
    bf16x8 nKa1 = *(const bf16x8*)(kh + (size_t)(kt2 + 16 + c) * DH + Q0 * 8);
    bf16x8 nVa0 = *(const bf16x8*)(v0h + kt + Q0 * 8);
    bf16x8 nVa1 = *(const bf16x8*)(v1h + kt + Q0 * 8);

    // S(t) = K(t) . Q^T  (8 MFMA)
    f32x4 s0[4], s1[4];
#pragma unroll
    for (int g = 0; g < 4; g++) {
      s0[g] = __builtin_amdgcn_mfma_f32_16x16x32_bf16(Ka0, Bq[g], zero, 0, 0, 0);
      s1[g] = __builtin_amdgcn_mfma_f32_16x16x32_bf16(Ka1, Bq[g], zero, 0, 0, 0);
    }

    // PV(t-1): operands already in registers (8 MFMA)
#pragma unroll
    for (int g = 0; g < 4; g++) {
      o0[g] = __builtin_amdgcn_mfma_f32_16x16x32_bf16(Vr0, Bp[g], o0[g], 0, 0, 0);
      o1[g] = __builtin_amdgcn_mfma_f32_16x16x32_bf16(Vr1, Bp[g], o1[g], 0, 0, 0);
    }

    // p = 2^s, lsum, pack, LDS round-trip for P(t)
#pragma unroll
    for (int g = 0; g < 4; g++) {
      float p0[4], p1[4];
#pragma unroll
      for (int r = 0; r < 4; r++) { p0[r] = EXP2F(s0[g][r]); lsum[g] += p0[r]; }
#pragma unroll
      for (int r = 0; r < 4; r++) { p1[r] = EXP2F(s1[g][r]); lsum[g] += p1[r]; }
      *(uint2*)(prow[g] + 4 * Q0)      = (uint2){pk2(p0[0], p0[1]), pk2(p0[2], p0[3])};
      *(uint2*)(prow[g] + 16 + 4 * Q0) = (uint2){pk2(p1[0], p1[1]), pk2(p1[2], p1[3])};
    }
#pragma unroll
    for (int g = 0; g < 4; g++) Bp[g] = *(const bf16x8*)(prow[g] + 8 * Q0);

    Ka0 = nKa0; Ka1 = nKa1; Vr0 = nVa0; Vr1 = nVa1;
  }

  // drain: PV(last)
#pragma unroll
  for (int g = 0; g < 4; g++) {
    o0[g] = __builtin_amdgcn_mfma_f32_16x16x32_bf16(Vr0, Bp[g], o0[g], 0, 0, 0);
    o1[g] = __builtin_amdgcn_mfma_f32_16x16x32_bf16(Vr1, Bp[g], o1[g], 0, 0, 0);
  }

  // ---- split-K combine (exact: unnormalized partials add) ----
  float4* cb = (float4*)&Pbuf[0][0][0][0];          // 1152 float4
  float4* ob = cb + (size_t)pairq * 8 * 64;         // 8 float4-slots per pair
  __syncthreads();                                   // Pbuf P-reads all done
  if (half) {
#pragma unroll
    for (int g = 0; g < 4; g++) {
      ob[(g * 2 + 0) * 64 + lane] = (float4){o0[g][0], o0[g][1], o0[g][2], o0[g][3]};
      ob[(g * 2 + 1) * 64 + lane] = (float4){o1[g][0], o1[g][1], o1[g][2], o1[g][3]};
    }
    cb[1024 + pairq * 64 + lane] = (float4){lsum[0], lsum[1], lsum[2], lsum[3]};
  }
  __syncthreads();
  if (!half) {
    const float4 lo = cb[1024 + pairq * 64 + lane];
    const float ls[4] = {lsum[0] + lo.x, lsum[1] + lo.y, lsum[2] + lo.z, lsum[3] + lo.w};
#pragma unroll
    for (int g = 0; g < 4; g++) {
      const float4 a0 = ob[(g * 2 + 0) * 64 + lane];
      const float4 a1 = ob[(g * 2 + 1) * 64 + lane];
      float l = ls[g];
      l += __shfl_xor(l, 16);
      l += __shfl_xor(l, 32);
      const float inv = 1.0f / l;
      unsigned short* op =
          ao + ((size_t)(b * NPIX + q0 + 16 * g + c)) * CH + h * DH + 4 * Q0;
      *(uint2*)op = (uint2){pk2((o0[g][0] + a0.x) * inv, (o0[g][1] + a0.y) * inv),
                            pk2((o0[g][2] + a0.z) * inv, (o0[g][3] + a0.w) * inv)};
      *(uint2*)(op + 16) =
          (uint2){pk2((o1[g][0] + a1.x) * inv, (o1[g][1] + a1.y) * inv),
                  pk2((o1[g][2] + a1.z) * inv, (o1[g][3] + a1.w) * inv)};
    }
  }
}

// ---------------------------------------------------------------------------
// Output projection, bf16 MFMA.  Per batch b:
//   out[c][n] = sum_{c'} Pw[c,c'] * AO[n,c'] + bias[c],  M=384,N=1024,K=384
// ---------------------------------------------------------------------------
__global__ __launch_bounds__(256) void proj_mfma(
    const unsigned short* __restrict__ ao, const unsigned short* __restrict__ pwq,
    const float* __restrict__ bias, float* __restrict__ out) {
  __shared__ unsigned short As[128 * 32];
  __shared__ unsigned short Bs[128 * 32];
  const int b = blockIdx.z;
  const int m0 = blockIdx.y * 128;
  const int n0 = blockIdx.x * 128;
  const int tid = threadIdx.x, wave = tid >> 6, lane = tid & 63;
  const int wm = (wave >> 1) * 64, wn = (wave & 1) * 64;
  const int cc = lane & 15, quad = lane >> 4;

  const unsigned short* agp =
      pwq + (size_t)(m0 + wave * 16 + (lane >> 2)) * CH + (lane & 3) * 8;
  const unsigned short* bgp =
      ao + ((size_t)b * NPIX + n0 + wave * 16 + (lane >> 2)) * CH + (lane & 3) * 8;
  unsigned short* al = As + wave * 16 * 32;
  unsigned short* bl = Bs + wave * 16 * 32;

  f32x4 acc[4][4];
#pragma unroll
  for (int i = 0; i < 4; i++)
#pragma unroll
    for (int j = 0; j < 4; j++) acc[i][j] = (f32x4){0.f, 0.f, 0.f, 0.f};

  for (int k0 = 0; k0 < CH; k0 += 32) {
    GLOAD_LDS16(agp + k0, al);
    GLOAD_LDS16(agp + k0 + (size_t)64 * CH, al + 64 * 32);
    GLOAD_LDS16(bgp + k0, bl);
    GLOAD_LDS16(bgp + k0 + (size_t)64 * CH, bl + 64 * 32);
    __syncthreads();
    bf16x8 af[4], bfr[4];
#pragma unroll
    for (int t = 0; t < 4; t++)
      af[t] = *(const bf16x8*)(As + (wm + t * 16 + cc) * 32 + quad * 8);
#pragma unroll
    for (int t = 0; t < 4; t++)
      bfr[t] = *(const bf16x8*)(Bs + (wn + t * 16 + cc) * 32 + quad * 8);
#pragma unroll
    for (int i = 0; i < 4; i++)
#pragma unroll
      for (int j = 0; j < 4; j++)
        acc[i][j] = __builtin_amdgcn_mfma_f32_16x16x32_bf16(af[i], bfr[j], acc[i][j], 0, 0, 0);
    __syncthreads();
  }

#pragma unroll
  for (int mt = 0; mt < 4; mt++) {
    const int cbase = m0 + wm + mt * 16 + quad * 4;
    const float4 bi4 = *(const float4*)(bias + cbase);
#pragma unroll
    for (int nt = 0; nt < 4; nt++) {
      const int n = n0 + wn + nt * 16 + cc;
      float* op = out + ((size_t)b * CH + cbase) * NPIX + n;
      op[0 * NPIX] = acc[mt][nt][0] + bi4.x;
      op[1 * NPIX] = acc[mt][nt][1] + bi4.y;
      op[2 * NPIX] = acc[mt][nt][2] + bi4.z;
      op[3 * NPIX] = acc[mt][nt][3] + bi4.w;
    }
  }
}

extern "C" void kernel_launch(void* const* d_in, const int* in_sizes, int n_in,
                              void* d_out, int out_size, void* d_ws, size_t ws_size,
                              hipStream_t stream) {
  const float* x      = (const float*)d_in[0];  // [16,384,32,32]
  const float* qkv_w  = (const float*)d_in[1];  // [1152,384]
  const float* proj_w = (const float*)d_in[2];  // [384,384]
  const float* proj_b = (const float*)d_in[3];  // [384]

  constexpr size_t SEG = (size_t)NB * NPIX * CH;  // 6291456
  unsigned short* ws  = (unsigned short*)d_ws;
  unsigned short* xtw = ws;
  unsigned short* qbw = ws + SEG;
  unsigned short* kbw = ws + 2 * SEG;
  unsigned short* vtw = ws + 3 * SEG;
  unsigned short* aow = ws + 4 * SEG;
  unsigned short* wqw = ws + 5 * SEG;               // 442368
  unsigned short* pww = wqw + (size_t)3 * CH * CH;  // 147456

  prep_w<<<576, 256, 0, stream>>>(qkv_w, proj_w, wqw, pww);
  transpose_x<<<dim3(NPIX / 64, CH / 64, NB), 256, 0, stream>>>(x, xtw);
  qkv_mfma<<<dim3(NPIX / 128, (3 * CH) / 128, NB), 256, 0, stream>>>(xtw, wqw, qbw, kbw, vtw);
  // grid (bh, qtile-of-128): same-bh blocks share an XCD; waves split keys
  attn_mfma<<<dim3(NB * NHEAD, NPIX / 128), 256, 0, stream>>>(qbw, kbw, vtw, aow);
  proj_mfma<<<dim3(NPIX / 128, CH / 128, NB), 256, 0, stream>>>(aow, pww, proj_b, (float*)d_out);
}

// Round 9
// 179.202 us; speedup vs baseline: 1.0784x; 1.0070x over previous
//
#include <hip/hip_runtime.h>

// Problem constants (fixed by the reference)
constexpr int CH    = 384;    // channels
constexpr int NPIX  = 1024;   // H*W = 32*32
constexpr int NHEAD = 12;
constexpr int DH    = 32;     // head dim
constexpr int NB    = 16;     // batch
constexpr float SCALE = 0.17677669529663689f;  // 32^-0.5
constexpr float LOG2E = 1.4426950408889634f;

typedef __attribute__((ext_vector_type(8))) short bf16x8;  // 8 bf16 (4 VGPRs)
typedef __attribute__((ext_vector_type(4))) float f32x4;   // MFMA C/D frag

// pack two fp32 -> two bf16, round-half-up (3 VALU)
__device__ __forceinline__ unsigned pk2(float a, float b) {
  return __builtin_amdgcn_perm(__float_as_uint(b) + 0x8000u,
                               __float_as_uint(a) + 0x8000u, 0x07060302u);
}
// pack two fp32 -> two bf16, TRUNCATE (1 VALU).  Used only for P in the attn
// hot loop: the truncation bias cancels exactly in P/l (l is summed from the
// same truncated values via the ones-MFMA).
__device__ __forceinline__ unsigned pk2t(float a, float b) {
  return __builtin_amdgcn_perm(__float_as_uint(b), __float_as_uint(a), 0x07060302u);
}

// 2^x on the VALU (v_exp_f32 computes 2^x natively)
#if __has_builtin(__builtin_amdgcn_exp2f)
#define EXP2F(x) __builtin_amdgcn_exp2f(x)
#else
#define EXP2F(x) exp2f(x)
#endif

// async global->LDS, 16 B per lane; LDS dest = wave-uniform base + lane*16
#define GLOAD_LDS16(g, l)                                               \
  __builtin_amdgcn_global_load_lds(                                     \
      (const __attribute__((address_space(1))) unsigned int*)(g),       \
      (__attribute__((address_space(3))) unsigned int*)(l), 16, 0, 0)

// ---------------------------------------------------------------------------
// Fused prep: blocks [0,1536) transpose x [b][c][n] fp32 -> xt [b][n][c] bf16;
// blocks [1536,2112) convert weights to bf16 (Q rows pre-scaled by
// SCALE*log2e so attention logits come out base-2 ready).
// ---------------------------------------------------------------------------
__global__ __launch_bounds__(256) void prep_fused(
    const float* __restrict__ x, const float* __restrict__ qw,
    const float* __restrict__ pw, unsigned short* __restrict__ xt,
    unsigned short* __restrict__ wq, unsigned short* __restrict__ pwq) {
  const int bx = blockIdx.x;
  const int tid = threadIdx.x;
  if (bx < 1536) {
    __shared__ float T[64][65];
    const int b = bx / 96, rem = bx - b * 96;
    const int c0 = (rem >> 4) * 64, n0 = (rem & 15) * 64;
    const float* xb = x + ((size_t)b * CH + c0) * NPIX + n0;
    const int rn = (tid & 15) * 4, rc = tid >> 4;
#pragma unroll
    for (int i = 0; i < 4; i++) {
      float4 v = *(const float4*)(xb + (size_t)(rc + i * 16) * NPIX + rn);
      T[rc + i * 16][rn + 0] = v.x;
      T[rc + i * 16][rn + 1] = v.y;
      T[rc + i * 16][rn + 2] = v.z;
      T[rc + i * 16][rn + 3] = v.w;
    }
    __syncthreads();
    unsigned short* xo = xt + ((size_t)b * NPIX + n0) * CH + c0;
    const int wc = (tid & 15) * 4, wn = tid >> 4;
#pragma unroll
    for (int i = 0; i < 4; i++) {
      const int n = wn + i * 16;
      uint2 p = {pk2(T[wc][n], T[wc + 1][n]), pk2(T[wc + 2][n], T[wc + 3][n])};
      *(uint2*)(xo + (size_t)n * CH + wc) = p;
    }
  } else {
    const int idx = (bx - 1536) * 256 + tid;
    if (idx < 110592) {
      float4 v = ((const float4*)qw)[idx];
      const int o = (idx * 4) / CH;  // 4 | 384: never crosses a row
      const float sc = (o < CH) ? SCALE * LOG2E : 1.0f;
      ((uint2*)wq)[idx] = (uint2){pk2(v.x * sc, v.y * sc), pk2(v.z * sc, v.w * sc)};
    } else {
      const int j = idx - 110592;
      float4 v = ((const float4*)pw)[j];
      ((uint2*)pwq)[j] = (uint2){pk2(v.x, v.y), pk2(v.z, v.w)};
    }
  }
}

// ---------------------------------------------------------------------------
// QKV GEMM, bf16 MFMA.  Per batch b:
//   Y[o,n] = sum_c Wq[o,c] * XT[n,c],  M=1152, N=1024, K=384
// V-blocks swap MFMA operands so C-frag rows = consecutive pixels ->
// vectorized d-major stores.
// ---------------------------------------------------------------------------
__global__ __launch_bounds__(256) void qkv_mfma(
    const unsigned short* __restrict__ xt, const unsigned short* __restrict__ wq,
    unsigned short* __restrict__ qb, unsigned short* __restrict__ kb,
    unsigned short* __restrict__ vtb) {
  __shared__ unsigned short As[128 * 32];  // [m(o)][k] rows of 64 B
  __shared__ unsigned short Bs[128 * 32];  // [n(pix)][k]
  const int b = blockIdx.z;
  const int m0 = blockIdx.y * 128;
  const int n0 = blockIdx.x * 128;
  const int tid = threadIdx.x, wave = tid >> 6, lane = tid & 63;
  const int wm = (wave >> 1) * 64, wn = (wave & 1) * 64;
  const int cc = lane & 15, quad = lane >> 4;
  const int qkv_t = blockIdx.y / 3;  // 0=Q, 1=K, 2=V

  const unsigned short* agp =
      wq + (size_t)(m0 + wave * 16 + (lane >> 2)) * CH + (lane & 3) * 8;
  const unsigned short* bgp =
      xt + ((size_t)b * NPIX + n0 + wave * 16 + (lane >> 2)) * CH + (lane & 3) * 8;
  unsigned short* al = As + wave * 16 * 32;
  unsigned short* bl = Bs + wave * 16 * 32;

  f32x4 acc[4][4];
#pragma unroll
  for (int i = 0; i < 4; i++)
#pragma unroll
    for (int j = 0; j < 4; j++) acc[i][j] = (f32x4){0.f, 0.f, 0.f, 0.f};

  for (int k0 = 0; k0 < CH; k0 += 32) {
    GLOAD_LDS16(agp + k0, al);
    GLOAD_LDS16(agp + k0 + (size_t)64 * CH, al + 64 * 32);
    GLOAD_LDS16(bgp + k0, bl);
    GLOAD_LDS16(bgp + k0 + (size_t)64 * CH, bl + 64 * 32);
    __syncthreads();
    bf16x8 af[4], bfr[4];
    if (qkv_t < 2) {
#pragma unroll
      for (int t = 0; t < 4; t++)
        af[t] = *(const bf16x8*)(As + (wm + t * 16 + cc) * 32 + quad * 8);
#pragma unroll
      for (int t = 0; t < 4; t++)
        bfr[t] = *(const bf16x8*)(Bs + (wn + t * 16 + cc) * 32 + quad * 8);
    } else {  // V: swap roles -> C rows = pixels
#pragma unroll
      for (int t = 0; t < 4; t++)
        af[t] = *(const bf16x8*)(Bs + (wn + t * 16 + cc) * 32 + quad * 8);
#pragma unroll
      for (int t = 0; t < 4; t++)
        bfr[t] = *(const bf16x8*)(As + (wm + t * 16 + cc) * 32 + quad * 8);
    }
#pragma unroll
    for (int i = 0; i < 4; i++)
#pragma unroll
      for (int j = 0; j < 4; j++)
        acc[i][j] = __builtin_amdgcn_mfma_f32_16x16x32_bf16(af[i], bfr[j], acc[i][j], 0, 0, 0);
    __syncthreads();
  }

  const int obase = m0 - qkv_t * CH;  // 0/128/256 within the Q/K/V segment
  if (qkv_t < 2) {
    unsigned short* dst0 = (qkv_t == 0) ? qb : kb;
#pragma unroll
    for (int mt = 0; mt < 4; mt++) {
      const int o = obase + wm + mt * 16 + quad * 4;  // [0,384)
      const int h = o >> 5, d0 = o & 31;
      unsigned short* drow = dst0 + ((size_t)(b * NHEAD + h) * NPIX) * DH + d0;
#pragma unroll
      for (int nt = 0; nt < 4; nt++) {
        const int n = n0 + wn + nt * 16 + cc;
        uint2 p = {pk2(acc[mt][nt][0], acc[mt][nt][1]),
                   pk2(acc[mt][nt][2], acc[mt][nt][3])};
        *(uint2*)(drow + (size_t)n * DH) = p;
      }
    }
  } else {
#pragma unroll
    for (int i = 0; i < 4; i++) {
      const int nbase = n0 + wn + i * 16 + quad * 4;
#pragma unroll
      for (int j = 0; j < 4; j++) {
        const int od = obase + wm + j * 16 + cc;
        const int h = od >> 5, dd = od & 31;
        unsigned short* vrow = vtb + ((size_t)(b * NHEAD + h) * DH + dd) * NPIX;
        *(uint2*)(vrow + nbase) = (uint2){pk2(acc[i][j][0], acc[i][j][1]),
                                          pk2(acc[i][j][2], acc[i][j][3])};
      }
    }
  }
}

// ---------------------------------------------------------------------------
// MFMA attention v9: VALU-diet.  One wave = 64 queries (R6 amortization:
// best MFMA-per-load), grid (192, 4) = 768 blocks, XCD-pinned (192%8==0).
// VALU cuts vs R6:
//   - softmax denominator on the MATRIX pipe: l[q] = ones-row MFMA over the
//     same truncated-bf16 P the PV uses (deletes 32 serial adds/iter AND the
//     final shfl reduce; denominator exactly consistent with numerator).
//   - P packed by truncation (pk2t, 1 VALU/pair vs 3): truncation bias is
//     scale-invariant in P/l, only ~0.2% rms variation remains.
// Skewed pipeline (PV/l-MFMA consume iteration t-1's registers) retained.
// ---------------------------------------------------------------------------
__global__ __launch_bounds__(256, 3) void attn_mfma(
    const unsigned short* __restrict__ qb, const unsigned short* __restrict__ kb,
    const unsigned short* __restrict__ vtb, unsigned short* __restrict__ ao) {
  constexpr int PSTR = 36;  // 72 B rows: 18c mod 32 hits all 16 even residues
  __shared__ unsigned short Pbuf[4][4][16][PSTR];  // [wave][qgroup][row][keys]

  const int bh   = blockIdx.x;  // 0..191  (x-major -> XCD = bh % 8)
  const int b    = bh / NHEAD;
  const int h    = bh - b * NHEAD;
  const int tid  = threadIdx.x;
  const int wave = tid >> 6;
  const int lane = tid & 63;
  const int c    = lane & 15;
  const int Q0   = lane >> 4;
  const int q0   = blockIdx.y * 256 + wave * 64;

  bf16x8 Bq[4];
#pragma unroll
  for (int g = 0; g < 4; g++)
    Bq[g] = *(const bf16x8*)(qb + ((size_t)bh * NPIX + q0 + 16 * g + c) * DH + Q0 * 8);

  const unsigned short* kbase = kb + (size_t)bh * NPIX * DH;
  const unsigned short* vrow0 = vtb + ((size_t)bh * DH + c) * NPIX;
  const unsigned short* vrow1 = vtb + ((size_t)bh * DH + c + 16) * NPIX;

  const f32x4 zero = {0.f, 0.f, 0.f, 0.f};
  const bf16x8 zero8 = {0, 0, 0, 0, 0, 0, 0, 0};
  const short ONE = (short)0x3F80;  // bf16 1.0
  const bf16x8 ones = {ONE, ONE, ONE, ONE, ONE, ONE, ONE, ONE};

  f32x4 o0[4], o1[4], ls[4];
#pragma unroll
  for (int g = 0; g < 4; g++) { o0[g] = zero; o1[g] = zero; ls[g] = zero; }

  unsigned short* prow[4];
#pragma unroll
  for (int g = 0; g < 4; g++) prow[g] = &Pbuf[wave][g][c][0];

  // pipeline registers
  bf16x8 Ka0 = *(const bf16x8*)(kbase + (size_t)c * DH + Q0 * 8);  // K(0)
  bf16x8 Ka1 = *(const bf16x8*)(kbase + (size_t)(16 + c) * DH + Q0 * 8);
  bf16x8 Vr0 = zero8, Vr1 = zero8;              // V(t-1); PV(-1) adds 0
  bf16x8 Bp[4] = {zero8, zero8, zero8, zero8};  // P(t-1)

#pragma unroll 2
  for (int kt = 0; kt < NPIX; kt += 32) {
    const int kt2 = (kt + 32) & (NPIX - 1);  // wrap on last iter (in-bounds)
    bf16x8 nKa0 = *(const bf16x8*)(kbase + (size_t)(kt2 + c) * DH + Q0 * 8);
    bf16x8 nKa1 = *(const bf16x8*)(kbase + (size_t)(kt2 + 16 + c) * DH + Q0 * 8);
    bf16x8 nVa0 = *(const bf16x8*)(vrow0 + kt + Q0 * 8);
    bf16x8 nVa1 = *(const bf16x8*)(vrow1 + kt + Q0 * 8);

    // S(t) = K(t) . Q^T  (8 MFMA)
    f32x4 s0[4], s1[4];
#pragma unroll
    for (int g = 0; g < 4; g++) {
      s0[g] = __builtin_amdgcn_mfma_f32_16x16x32_bf16(Ka0, Bq[g], zero, 0, 0, 0);
      s1[g] = __builtin_amdgcn_mfma_f32_16x16x32_bf16(Ka1, Bq[g], zero, 0, 0, 0);
    }

    // PV(t-1) + denominator(t-1): 12 MFMA, all operands in registers
#pragma unroll
    for (int g = 0; g < 4; g++) {
      o0[g] = __builtin_amdgcn_mfma_f32_16x16x32_bf16(Vr0, Bp[g], o0[g], 0, 0, 0);
      o1[g] = __builtin_amdgcn_mfma_f32_16x16x32_bf16(Vr1, Bp[g], o1[g], 0, 0, 0);
      ls[g] = __builtin_amdgcn_mfma_f32_16x16x32_bf16(ones, Bp[g], ls[g], 0, 0, 0);
    }

    // p = 2^s (Q pre-scaled by log2e), truncate-pack, LDS round-trip
#pragma unroll
    for (int g = 0; g < 4; g++) {
      float p0[4], p1[4];
#pragma unroll
      for (int r = 0; r < 4; r++) p0[r] = EXP2F(s0[g][r]);
#pragma unroll
      for (int r = 0; r < 4; r++) p1[r] = EXP2F(s1[g][r]);
      *(uint2*)(prow[g] + 4 * Q0)      = (uint2){pk2t(p0[0], p0[1]), pk2t(p0[2], p0[3])};
      *(uint2*)(prow[g] + 16 + 4 * Q0) = (uint2){pk2t(p1[0], p1[1]), pk2t(p1[2], p1[3])};
    }
#pragma unroll
    for (int g = 0; g < 4; g++) Bp[g] = *(const bf16x8*)(prow[g] + 8 * Q0);

    Ka0 = nKa0; Ka1 = nKa1; Vr0 = nVa0; Vr1 = nVa1;
  }

  // drain: PV(last) + denominator(last)
#pragma unroll
  for (int g = 0; g < 4; g++) {
    o0[g] = __builtin_amdgcn_mfma_f32_16x16x32_bf16(Vr0, Bp[g], o0[g], 0, 0, 0);
    o1[g] = __builtin_amdgcn_mfma_f32_16x16x32_bf16(Vr1, Bp[g], o1[g], 0, 0, 0);
    ls[g] = __builtin_amdgcn_mfma_f32_16x16x32_bf16(ones, Bp[g], ls[g], 0, 0, 0);
  }

#pragma unroll
  for (int g = 0; g < 4; g++) {
    const float inv = 1.0f / ls[g][0];  // all regs/rows identical = full l[q]
    unsigned short* op =
        ao + ((size_t)(b * NPIX + q0 + 16 * g + c)) * CH + h * DH + 4 * Q0;
    *(uint2*)op = (uint2){pk2(o0[g][0] * inv, o0[g][1] * inv),
                          pk2(o0[g][2] * inv, o0[g][3] * inv)};
    *(uint2*)(op + 16) = (uint2){pk2(o1[g][0] * inv, o1[g][1] * inv),
                                 pk2(o1[g][2] * inv, o1[g][3] * inv)};
  }
}

// ---------------------------------------------------------------------------
// Output projection, bf16 MFMA, 128m x 64n tiles (768 blocks = 3/CU; the old
// 128x128 grid was 384 blocks = 1.5/CU, half the CUs idled).
//   out[c][n] = sum_{c'} Pw[c,c'] * AO[n,c'] + bias[c],  M=384,N=1024,K=384
// ---------------------------------------------------------------------------
__global__ __launch_bounds__(256) void proj_mfma(
    const unsigned short* __restrict__ ao, const unsigned short* __restrict__ pwq,
    const float* __restrict__ bias, float* __restrict__ out) {
  __shared__ unsigned short As[128 * 32];  // 8 KB
  __shared__ unsigned short Bs[64 * 32];   // 4 KB
  const int b = blockIdx.z;
  const int m0 = blockIdx.y * 128;
  const int n0 = blockIdx.x * 64;
  const int tid = threadIdx.x, wave = tid >> 6, lane = tid & 63;
  const int wm = (wave >> 1) * 64, wn = (wave & 1) * 32;
  const int cc = lane & 15, quad = lane >> 4;

  // A staging: wave covers rows wave*32..+31 (two 16-row GLOADs)
  const unsigned short* agp0 =
      pwq + (size_t)(m0 + wave * 32 + (lane >> 2)) * CH + (lane & 3) * 8;
  const unsigned short* agp1 = agp0 + (size_t)16 * CH;
  unsigned short* al0 = As + wave * 32 * 32;
  unsigned short* al1 = al0 + 16 * 32;
  // B staging: wave covers rows wave*16..+15 (one GLOAD)
  const unsigned short* bgp =
      ao + ((size_t)b * NPIX + n0 + wave * 16 + (lane >> 2)) * CH + (lane & 3) * 8;
  unsigned short* bl = Bs + wave * 16 * 32;

  f32x4 acc[4][2];
#pragma unroll
  for (int i = 0; i < 4; i++)
#pragma unroll
    for (int j = 0; j < 2; j++) acc[i][j] = (f32x4){0.f, 0.f, 0.f, 0.f};

  for (int k0 = 0; k0 < CH; k0 += 32) {
    GLOAD_LDS16(agp0 + k0, al0);
    GLOAD_LDS16(agp1 + k0, al1);
    GLOAD_LDS16(bgp + k0, bl);
    __syncthreads();
    bf16x8 af[4], bfr[2];
#pragma unroll
    for (int t = 0; t < 4; t++)
      af[t] = *(const bf16x8*)(As + (wm + t * 16 + cc) * 32 + quad * 8);
#pragma unroll
    for (int t = 0; t < 2; t++)
      bfr[t] = *(const bf16x8*)(Bs + (wn + t * 16 + cc) * 32 + quad * 8);
#pragma unroll
    for (int i = 0; i < 4; i++)
#pragma unroll
      for (int j = 0; j < 2; j++)
        acc[i][j] = __builtin_amdgcn_mfma_f32_16x16x32_bf16(af[i], bfr[j], acc[i][j], 0, 0, 0);
    __syncthreads();
  }

#pragma unroll
  for (int mt = 0; mt < 4; mt++) {
    const int cbase = m0 + wm + mt * 16 + quad * 4;
    const float4 bi4 = *(const float4*)(bias + cbase);
#pragma unroll
    for (int nt = 0; nt < 2; nt++) {
      const int n = n0 + wn + nt * 16 + cc;
      float* op = out + ((size_t)b * CH + cbase) * NPIX + n;
      op[0 * NPIX] = acc[mt][nt][0] + bi4.x;
      op[1 * NPIX] = acc[mt][nt][1] + bi4.y;
      op[2 * NPIX] = acc[mt][nt][2] + bi4.z;
      op[3 * NPIX] = acc[mt][nt][3] + bi4.w;
    }
  }
}

extern "C" void kernel_launch(void* const* d_in, const int* in_sizes, int n_in,
                              void* d_out, int out_size, void* d_ws, size_t ws_size,
                              hipStream_t stream) {
  const float* x      = (const float*)d_in[0];  // [16,384,32,32]
  const float* qkv_w  = (const float*)d_in[1];  // [1152,384]
  const float* proj_w = (const float*)d_in[2];  // [384,384]
  const float* proj_b = (const float*)d_in[3];  // [384]

  constexpr size_t SEG = (size_t)NB * NPIX * CH;  // 6291456
  unsigned short* ws  = (unsigned short*)d_ws;
  unsigned short* xtw = ws;
  unsigned short* qbw = ws + SEG;
  unsigned short* kbw = ws + 2 * SEG;
  unsigned short* vtw = ws + 3 * SEG;
  unsigned short* aow = ws + 4 * SEG;
  unsigned short* wqw = ws + 5 * SEG;               // 442368
  unsigned short* pww = wqw + (size_t)3 * CH * CH;  // 147456

  prep_fused<<<2112, 256, 0, stream>>>(x, qkv_w, proj_w, xtw, wqw, pww);
  qkv_mfma<<<dim3(NPIX / 128, (3 * CH) / 128, NB), 256, 0, stream>>>(xtw, wqw, qbw, kbw, vtw);
  // grid (bh, qtile): same-bh blocks share an XCD -> K/V L2-resident
  attn_mfma<<<dim3(NB * NHEAD, NPIX / 256), 256, 0, stream>>>(qbw, kbw, vtw, aow);
  proj_mfma<<<dim3(NPIX / 64, CH / 128, NB), 256, 0, stream>>>(aow, pww, proj_b, (float*)d_out);
}